// Round 3
// baseline (1072.872 us; speedup 1.0000x reference)
//
#include <hip/hip_runtime.h>
#include <stdint.h>

#define T_TOK 8192
#define HID   4096
#define NOUT  6144
#define S_SLOTS 8
#define TPAD_MAX 9216   // 8192 + 8*128 worst-case per-slot padding
#define NKT 128         // HID / 32 K-tiles

typedef __attribute__((ext_vector_type(8))) short bf16x8;
typedef __attribute__((ext_vector_type(4))) float f32x4;

__device__ __forceinline__ unsigned short f2bf(float f) {
  union { float f; unsigned u; } v; v.f = f;
  unsigned r = v.u + 0x7FFFu + ((v.u >> 16) & 1u);   // RNE
  return (unsigned short)(r >> 16);
}

__device__ __forceinline__ f32x4 mfma32(bf16x8 a, bf16x8 b, f32x4 c) {
  return __builtin_amdgcn_mfma_f32_16x16x32_bf16(a, b, c, 0, 0, 0);
}

__device__ __forceinline__ void glds16(const void* g, void* l) {
  __builtin_amdgcn_global_load_lds(
      (const __attribute__((address_space(1))) unsigned int*)g,
      (__attribute__((address_space(3))) unsigned int*)l, 16, 0, 0);
}

// ---------------- sort tokens by slot, pad each slot range to 128 ----------------
__global__ void k_sort(const int* __restrict__ t2s, int* __restrict__ perm,
                       int* __restrict__ slotarr, int* __restrict__ meta) {
  __shared__ int cnt[8], cur[8], padoff[9];
  int tid = threadIdx.x;
  if (tid < 8) cnt[tid] = 0;
  __syncthreads();
  for (int t = tid; t < T_TOK; t += 256) atomicAdd(&cnt[t2s[t]], 1);
  __syncthreads();
  if (tid == 0) {
    int o = 0;
    for (int s = 0; s < 8; ++s) { padoff[s] = o; o += ((cnt[s] + 127) >> 7) << 7; }
    padoff[8] = o;
    meta[0] = o;  // Tpad
  }
  __syncthreads();
  if (tid < 8) cur[tid] = padoff[tid];
  int Tpad = padoff[8];
  for (int p = tid; p < TPAD_MAX; p += 256) {
    int s = 0;
    if (p < Tpad) { while (s < 7 && p >= padoff[s + 1]) ++s; }
    perm[p] = -1;
    slotarr[p] = s;
  }
  __syncthreads();
  for (int t = tid; t < T_TOK; t += 256) {
    int s = t2s[t];
    int pos = atomicAdd(&cur[s], 1);
    perm[pos] = t;
  }
}

// ---------------- f32 -> bf16 bulk convert ----------------
__global__ void k_convert(const float* __restrict__ src, unsigned short* __restrict__ dst, int n8) {
  int i = blockIdx.x * blockDim.x + threadIdx.x;
  int stride = gridDim.x * blockDim.x;
  for (; i < n8; i += stride) {
    const f32x4* s = (const f32x4*)src + (size_t)i * 2;
    f32x4 a = s[0], b = s[1];
    bf16x8 o;
    o[0]=(short)f2bf(a[0]); o[1]=(short)f2bf(a[1]); o[2]=(short)f2bf(a[2]); o[3]=(short)f2bf(a[3]);
    o[4]=(short)f2bf(b[0]); o[5]=(short)f2bf(b[1]); o[6]=(short)f2bf(b[2]); o[7]=(short)f2bf(b[3]);
    *((bf16x8*)dst + i) = o;
  }
}

// ---------------- x: gather by perm + convert; zero dummy rows ----------------
__global__ void k_convert_x(const float* __restrict__ x, const int* __restrict__ perm,
                            const int* __restrict__ meta, unsigned short* __restrict__ xb) {
  int p = blockIdx.x;
  int Tpad = meta[0];
  int t = (p < Tpad) ? perm[p] : -1;
  bf16x8* drow = (bf16x8*)(xb + (size_t)p * HID);
  int tid = threadIdx.x;
  if (t >= 0) {
    const f32x4* srow = (const f32x4*)(x + (size_t)t * HID);
    for (int j = tid; j < HID / 8; j += 256) {
      f32x4 a = srow[j * 2], b = srow[j * 2 + 1];
      bf16x8 o;
      o[0]=(short)f2bf(a[0]); o[1]=(short)f2bf(a[1]); o[2]=(short)f2bf(a[2]); o[3]=(short)f2bf(a[3]);
      o[4]=(short)f2bf(b[0]); o[5]=(short)f2bf(b[1]); o[6]=(short)f2bf(b[2]); o[7]=(short)f2bf(b[3]);
      drow[j] = o;
    }
  } else {
    bf16x8 z = {0,0,0,0,0,0,0,0};
    for (int j = tid; j < HID / 8; j += 256) drow[j] = z;
  }
}

// ---------------- Bq|Bk|Bv -> concatenated bf16 [S][6144][16] ----------------
__global__ void k_convert_B(const float* __restrict__ Bq, const float* __restrict__ Bk,
                            const float* __restrict__ Bv, unsigned short* __restrict__ Bb) {
  int i = blockIdx.x * blockDim.x + threadIdx.x;
  int stride = gridDim.x * blockDim.x;
  const int total = S_SLOTS * NOUT * 16;
  for (; i < total; i += stride) {
    int s = i / (NOUT * 16);
    int rem = i - s * (NOUT * 16);
    int col = rem >> 4, r = rem & 15;
    float v;
    if (col < 4096)      v = Bq[((size_t)s * 4096 + col) * 16 + r];
    else if (col < 5120) v = Bk[((size_t)s * 1024 + (col - 4096)) * 16 + r];
    else                 v = Bv[((size_t)s * 1024 + (col - 5120)) * 16 + r];
    Bb[i] = f2bf(v);
  }
}

// ---------------- a[p, 48] = scaling[s] * xb[p] @ A[s]^T   (bf16 out) ----------------
__global__ __launch_bounds__(256) void k_loraA(
    const unsigned short* __restrict__ xb, const unsigned short* __restrict__ Ab,
    const float* __restrict__ scaling, const int* __restrict__ slotarr,
    const int* __restrict__ meta, unsigned short* __restrict__ abf) {
  int p0 = blockIdx.x * 32;
  int Tpad = meta[0];
  if (p0 >= Tpad) return;
  __shared__ float red[3][64 * 24];
  int tid = threadIdx.x, lane = tid & 63, wid = tid >> 6;
  int s = slotarr[p0];
  const unsigned short* A_s = Ab + (size_t)s * 48 * HID;
  int r = lane & 15, g = lane >> 4;
  f32x4 acc[2][3] = {};
  int kbase = wid * (HID / 4);
  for (int k = kbase; k < kbase + HID / 4; k += 32) {
    const unsigned short* xk = xb + (size_t)p0 * HID + k + g * 8;
    bf16x8 a0 = *(const bf16x8*)(xk + (size_t)r * HID);
    bf16x8 a1 = *(const bf16x8*)(xk + (size_t)(r + 16) * HID);
    const unsigned short* ak = A_s + k + g * 8;
    bf16x8 b0 = *(const bf16x8*)(ak + (size_t)r * HID);
    bf16x8 b1 = *(const bf16x8*)(ak + (size_t)(r + 16) * HID);
    bf16x8 b2 = *(const bf16x8*)(ak + (size_t)(r + 32) * HID);
    acc[0][0] = mfma32(a0, b0, acc[0][0]);
    acc[0][1] = mfma32(a0, b1, acc[0][1]);
    acc[0][2] = mfma32(a0, b2, acc[0][2]);
    acc[1][0] = mfma32(a1, b0, acc[1][0]);
    acc[1][1] = mfma32(a1, b1, acc[1][1]);
    acc[1][2] = mfma32(a1, b2, acc[1][2]);
  }
  if (wid > 0) {
    float* dst = &red[wid - 1][lane * 24];
    for (int m = 0; m < 2; ++m)
      for (int n = 0; n < 3; ++n)
        for (int reg = 0; reg < 4; ++reg) dst[(m * 3 + n) * 4 + reg] = acc[m][n][reg];
  }
  __syncthreads();
  if (wid == 0) {
    float sc = scaling[s];
    for (int m = 0; m < 2; ++m)
      for (int n = 0; n < 3; ++n)
        for (int reg = 0; reg < 4; ++reg) {
          int idx = (m * 3 + n) * 4 + reg;
          float v = acc[m][n][reg] + red[0][lane * 24 + idx] + red[1][lane * 24 + idx] +
                    red[2][lane * 24 + idx];
          int row = p0 + m * 16 + g * 4 + reg;
          abf[(size_t)row * 48 + n * 16 + r] = f2bf(v * sc);
        }
  }
}

// ---------------- main GEMM: 256x256 tile, BK=32, ring-4 LDS, counted vmcnt ----------------
// 8 waves (2M x 4N), per-wave 128x64 output. Fused LoRA K=16 tail per 128-row half.
__global__ __launch_bounds__(512, 2) void k_gemm(
    const unsigned short* __restrict__ xb, const unsigned short* __restrict__ Wb,
    const unsigned short* __restrict__ abf, const unsigned short* __restrict__ Bb,
    const int* __restrict__ perm, const int* __restrict__ slotarr,
    const int* __restrict__ meta, float* __restrict__ out) {
  __shared__ __align__(16) unsigned short As[4][256 * 32];   // 64 KB ring
  __shared__ __align__(16) unsigned short Bs[4][256 * 32];   // 64 KB ring
  __shared__ __align__(16) unsigned short As2[256 * 16];     // 8 KB  LoRA a-slice
  __shared__ __align__(16) unsigned short Bs2[2][256 * 16];  // 16 KB LoRA B per row-half

  const int Tpad = meta[0];
  const int nbm = (Tpad + 255) >> 8;
  const int nwg = nbm * 24;
  const int bid = (int)blockIdx.x;
  if (bid >= nwg) return;
  // bijective XCD swizzle (m204 form)
  const int q = nwg >> 3, r = nwg & 7;
  const int xcd = bid & 7, pos = bid >> 3;
  const int swz = (xcd < r ? xcd * (q + 1) : r * (q + 1) + (xcd - r) * q) + pos;
  // 4-wide bn bands, bm-major inside: concurrent tiles share B panels in L2
  const int bw = nbm << 2;
  const int band = swz / bw, rem = swz - band * bw;
  const int bm = rem >> 2, bn = (band << 2) + (rem & 3);

  const int tid = threadIdx.x, lane = tid & 63, wid = tid >> 6;
  const int wm = wid >> 2, wn = wid & 3;
  const int rowA0 = bm << 8;
  const int rowB0 = bn << 8;
  const int tgt = (bn >= 20) ? 2 : (bn >= 16) ? 1 : 0;
  const int s0 = slotarr[rowA0];
  const int s1 = slotarr[rowA0 + 128];

  const unsigned short* xg = xb + (size_t)rowA0 * HID;
  const unsigned short* wg = Wb + (size_t)rowB0 * HID;

  // ---- ext stage (3 ops/thread, oldest in vmcnt order): LoRA fold operands ----
  {
    int i = tid;
    glds16(abf + (size_t)(rowA0 + (i >> 1)) * 48 + tgt * 16 + (i & 1) * 8,
           (char*)As2 + ((i >> 6) << 10));
    #pragma unroll
    for (int j = 0; j < 2; ++j) {
      int ii = j * 512 + tid;
      int h = ii >> 9, rr = (ii >> 1) & 255, hf = ii & 1;
      int sh = h ? s1 : s0;
      glds16(Bb + ((size_t)sh * NOUT + rowB0 + rr) * 16 + hf * 8,
             (char*)Bs2 + ((ii >> 6) << 10));
    }
  }

  // ---- stage one K-tile (4 ops/thread): linear LDS [row][32k], BK=32 is bank-balanced ----
  auto stage = [&](int kt) {
    unsigned short* Ad = As[kt & 3];
    unsigned short* Bd = Bs[kt & 3];
    const int k0 = kt << 5;
    #pragma unroll
    for (int j = 0; j < 2; ++j) {
      int i = j * 512 + tid;
      int row = i >> 2, kc = i & 3;
      glds16(xg + (size_t)row * HID + k0 + kc * 8, (char*)Ad + ((i >> 6) << 10));
      glds16(wg + (size_t)row * HID + k0 + kc * 8, (char*)Bd + ((i >> 6) << 10));
    }
  };

  f32x4 acc[8][4] = {};
  const int lr = lane & 15, kg = lane >> 4;
  const int jb = kg << 4;

  auto compute = [&](int kt) {
    const char* Ap = (const char*)As[kt & 3];
    const char* Bp = (const char*)Bs[kt & 3];
    bf16x8 af[8], bfr[4];
    #pragma unroll
    for (int m = 0; m < 8; ++m)
      af[m] = *(const bf16x8*)(Ap + ((wm << 7) + (m << 4) + lr) * 64 + jb);
    #pragma unroll
    for (int n = 0; n < 4; ++n)
      bfr[n] = *(const bf16x8*)(Bp + ((wn << 6) + (n << 4) + lr) * 64 + jb);
    __builtin_amdgcn_s_setprio(1);
    #pragma unroll
    for (int m = 0; m < 8; ++m)
      #pragma unroll
      for (int n = 0; n < 4; ++n) acc[m][n] = mfma32(af[m], bfr[n], acc[m][n]);
    __builtin_amdgcn_s_setprio(0);
  };

  // ---- prologue: fill 3 ring slots; retire ext + tile0; publish ----
  stage(0); stage(1); stage(2);
  asm volatile("s_waitcnt vmcnt(8)" ::: "memory");
  __builtin_amdgcn_s_barrier();
  __builtin_amdgcn_sched_barrier(0);

  // ---- main loop: loads for 2-3 tiles always in flight; never drain vmcnt to 0 ----
  for (int kt = 0; kt < NKT - 3; ++kt) {
    stage(kt + 3);              // writes slot (kt-1)&3: reads done before last barrier
    compute(kt);
    asm volatile("s_waitcnt vmcnt(8)" ::: "memory");  // tile kt+1 landed (mine)
    __builtin_amdgcn_s_barrier();                      // ...and everyone's
    __builtin_amdgcn_sched_barrier(0);
  }
  compute(NKT - 3);
  asm volatile("s_waitcnt vmcnt(4)" ::: "memory");
  __builtin_amdgcn_s_barrier();
  __builtin_amdgcn_sched_barrier(0);
  compute(NKT - 2);
  asm volatile("s_waitcnt vmcnt(0)" ::: "memory");
  __builtin_amdgcn_s_barrier();
  __builtin_amdgcn_sched_barrier(0);
  compute(NKT - 1);

  // ---- fused LoRA tail: K=16 (lanes>=32 zeroed), B-slice per 128-row half ----
  {
    bf16x8 z = {0, 0, 0, 0, 0, 0, 0, 0};
    bf16x8 a2[8], b2[4];
    #pragma unroll
    for (int m = 0; m < 8; ++m) {
      a2[m] = z;
      if (lane < 32) {
        int row = (wm << 7) + (m << 4) + lr;
        a2[m] = *(const bf16x8*)((const char*)As2 + row * 32 + jb);
      }
    }
    #pragma unroll
    for (int n = 0; n < 4; ++n) {
      b2[n] = z;
      if (lane < 32) {
        int col = (wn << 6) + (n << 4) + lr;
        b2[n] = *(const bf16x8*)((const char*)Bs2 + wm * 8192 + col * 32 + jb);
      }
    }
    #pragma unroll
    for (int m = 0; m < 8; ++m)
      #pragma unroll
      for (int n = 0; n < 4; ++n) acc[m][n] = mfma32(a2[m], b2[n], acc[m][n]);
  }

  // ---- epilogue: scatter rows to out[perm[p]]; dummy rows masked ----
  const int colbase = (bn << 8) + (wn << 6);
  #pragma unroll
  for (int m = 0; m < 8; ++m) {
    #pragma unroll
    for (int reg = 0; reg < 4; ++reg) {
      int p = rowA0 + (wm << 7) + (m << 4) + ((lane >> 4) << 2) + reg;
      int t = perm[p];
      if (t < 0) continue;
      float* orow = out + (size_t)t * NOUT + colbase + (lane & 15);
      #pragma unroll
      for (int n = 0; n < 4; ++n) orow[n << 4] = acc[m][n][reg];
    }
  }
}

// ---------------- launcher ----------------
extern "C" void kernel_launch(void* const* d_in, const int* in_sizes, int n_in,
                              void* d_out, int out_size, void* d_ws, size_t ws_size,
                              hipStream_t stream) {
  const float* x  = (const float*)d_in[0];
  const float* W  = (const float*)d_in[1];
  const float* lA = (const float*)d_in[2];
  const float* Bq = (const float*)d_in[3];
  const float* Bk = (const float*)d_in[4];
  const float* Bv = (const float*)d_in[5];
  const float* sc = (const float*)d_in[6];
  const int* t2s  = (const int*)d_in[7];
  float* out = (float*)d_out;

  char* ws = (char*)d_ws;
  int* perm    = (int*)(ws + 0);                         // 9216 ints
  int* slotarr = (int*)(ws + 36864);                     // 9216 ints
  int* meta    = (int*)(ws + 73728);                     // 64 ints
  unsigned short* abf = (unsigned short*)(ws + 73984);   // 9216*48 bf16
  unsigned short* xb  = (unsigned short*)(ws + 958720);  // 9216*4096 bf16
  unsigned short* Wb  = (unsigned short*)(ws + 76456192);   // 6144*4096 bf16
  unsigned short* Ab  = (unsigned short*)(ws + 126787840);  // 384*4096 bf16
  unsigned short* Bb  = (unsigned short*)(ws + 129933568);  // 8*6144*16 bf16

  hipLaunchKernelGGL(k_sort, dim3(1), dim3(256), 0, stream, t2s, perm, slotarr, meta);
  hipLaunchKernelGGL(k_convert, dim3(2048), dim3(256), 0, stream, W, Wb, NOUT * HID / 8);
  hipLaunchKernelGGL(k_convert, dim3(768), dim3(256), 0, stream, lA, Ab, S_SLOTS * 48 * HID / 8);
  hipLaunchKernelGGL(k_convert_B, dim3(768), dim3(256), 0, stream, Bq, Bk, Bv, Bb);
  hipLaunchKernelGGL(k_convert_x, dim3(TPAD_MAX), dim3(256), 0, stream, x, perm, meta, xb);
  hipLaunchKernelGGL(k_loraA, dim3(288), dim3(256), 0, stream, xb, Ab, sc, slotarr, meta, abf);
  hipLaunchKernelGGL(k_gemm, dim3(864), dim3(512), 0, stream, xb, Wb, abf, Bb, perm, slotarr, meta, out);
}